// Round 5
// baseline (263.327 us; speedup 1.0000x reference)
//
#include <hip/hip_runtime.h>
#include <stdint.h>

// GCN: out = relu(adj @ (x @ W) + b)
// x:[32,1024,128] f32, adj:[32,1024,1024] f32, W:[128,128] f32, b:[128] f32
// v6: barrier-free k2. Ledger (F+k1=160.6us): k2_v1(2-barrier)=60, v2(dbuf)=61,
//   stream=87, v4(4blk/CU)=69, v5(counted-vmcnt attempt)=67.6. Model: every
//   LDS variant drains ~1 mem-latency per K-step under barrier lockstep
//   (t ~ 16 x 900cy / blocks-per-CU). v5's asm "memory" clobbers forced
//   vmcnt(0) drains (SIInsertWaitcnts is conservative on clobber asm).
//   Fix: remove ALL cross-wave deps. Each wave owns 16 disjoint m-rows x 128n:
//   adj frags depth-1 reg-prefetched (HBM latency hidden across a full K-step),
//   ST frags read direct (L2-hot 256KB/batch slice), bb loads issued BEFORE
//   the adj prefetch so in-order vmcnt retirement keeps L2 waits off the HBM
//   chain. No LDS / no barriers / no inline asm in k2 -> only compiler-counted
//   scoreboard waits. K-order per output unchanged -> bit-identical result.
// k1 stays LDS-free streaming (~3us).

typedef short bf16x8 __attribute__((ext_vector_type(8)));       // 8 bf16 (4 VGPRs)
typedef float f32x4 __attribute__((ext_vector_type(4)));
typedef unsigned short u16x8 __attribute__((ext_vector_type(8)));

__device__ __forceinline__ unsigned short f2bf(float f) {
    uint32_t u = __builtin_bit_cast(uint32_t, f);
    u += 0x7FFFu + ((u >> 16) & 1u);   // RTNE
    return (unsigned short)(u >> 16);
}

__device__ __forceinline__ bf16x8 cvt8(f32x4 v0, f32x4 v1) {
    u16x8 p;
    p[0] = f2bf(v0.x); p[1] = f2bf(v0.y); p[2] = f2bf(v0.z); p[3] = f2bf(v0.w);
    p[4] = f2bf(v1.x); p[5] = f2bf(v1.y); p[6] = f2bf(v1.z); p[7] = f2bf(v1.w);
    return __builtin_bit_cast(bf16x8, p);
}

// ---------------- k0: WT[h][f] = bf16(W[f][h]) ----------------
__global__ __launch_bounds__(256) void k0_wt(const float* __restrict__ W,
                                             unsigned short* __restrict__ WT) {
    int o = blockIdx.x * 256 + threadIdx.x;  // flat over [h][f]
    int h = o >> 7, f = o & 127;
    WT[o] = f2bf(W[f * 128 + h]);
}

// ---------------- k1: ST[b][h][m] = sum_f WT[h][f] * x[b][m][f] ----------------
// D'[h][m] per block: 128 h x 64 m, K=128. LDS-free: A-frags direct from WT
// (bf16, L2-hot), B-frags direct from x rows (f32 -> cvt in reg).
__global__ __launch_bounds__(256) void k1_support(const float* __restrict__ x,
                                                  const unsigned short* __restrict__ WT,
                                                  unsigned short* __restrict__ ST) {
    int t = threadIdx.x;
    int wv = t >> 6, lane = t & 63, l16 = lane & 15, quad = lane >> 4;
    int wave_h = (wv & 1) * 64, wave_m = (wv >> 1) * 32;
    int node_base = blockIdx.x * 64;
    const float* xb = x + (size_t)node_base * 128;

    f32x4 acc[4][2];
#pragma unroll
    for (int ht = 0; ht < 4; ++ht)
#pragma unroll
        for (int mt = 0; mt < 2; ++mt) acc[ht][mt] = 0.f;

#pragma unroll
    for (int s = 0; s < 4; ++s) {
        int ko = s * 32 + quad * 8;
        bf16x8 a[4], bb[2];
#pragma unroll
        for (int ht = 0; ht < 4; ++ht)
            a[ht] = *(const bf16x8*)&WT[(wave_h + ht * 16 + l16) * 128 + ko];
#pragma unroll
        for (int mt = 0; mt < 2; ++mt) {
            const float* xr = xb + (size_t)(wave_m + mt * 16 + l16) * 128 + ko;
            bb[mt] = cvt8(*(const f32x4*)xr, *(const f32x4*)(xr + 4));
        }
#pragma unroll
        for (int ht = 0; ht < 4; ++ht)
#pragma unroll
            for (int mt = 0; mt < 2; ++mt)
                acc[ht][mt] = __builtin_amdgcn_mfma_f32_16x16x32_bf16(
                    a[ht], bb[mt], acc[ht][mt], 0, 0, 0);
    }

    int batch = blockIdx.x >> 4;
    int m_in_b = (blockIdx.x & 15) * 64;
#pragma unroll
    for (int ht = 0; ht < 4; ++ht)
#pragma unroll
        for (int mt = 0; mt < 2; ++mt) {
            int mcol = wave_m + mt * 16 + l16;
#pragma unroll
            for (int r = 0; r < 4; ++r) {
                int h = wave_h + ht * 16 + quad * 4 + r;
                ST[(((size_t)batch * 128 + h) << 10) + m_in_b + mcol] =
                    f2bf(acc[ht][mt][r]);
            }
        }
}

// ---------------- k2: out[b][m][n] = relu(sum_k adj[b][m][k]*S[b][k][n] + bias[n]) ----
// v6: grid 512, 4 waves/block, wave w owns m-rows [mbase+16w, +16) x 128 n.
// acc = 8 frags (j=0..7). Per K-step (full kb unroll):
//   1) 16x bb loads (ST, L2-hot, 16B/lane)          <- issued FIRST
//   2) 4x adj f32x4 loads for kb+1 -> aN            <- HBM prefetch, depth-1
//   3) cvt aC -> a0,a1; 16 MFMA (j x s)
//   4) aC <- aN
// No LDS, no barriers: waves free-run; compiler emits counted vmcnt only.
__global__ __launch_bounds__(256, 2) void k2_gcn(const float* __restrict__ adj,
                                                 const unsigned short* __restrict__ ST,
                                                 const float* __restrict__ bias,
                                                 float* __restrict__ out) {
    int t = threadIdx.x;
    int batch = blockIdx.x >> 4;
    int mbase = (blockIdx.x & 15) * 64;
    int wv = t >> 6, lane = t & 63, l16 = lane & 15, quad = lane >> 4;
    int wrow = mbase + wv * 16;                      // wave's 16 m-rows

    // per-lane adj row pointer (row = wrow + l16)
    const float* adjw = adj + ((size_t)batch * 1024 + wrow + l16) * 1024;
    const unsigned short* stb = ST + ((size_t)batch * 128) * 1024;

    float bv[8];
#pragma unroll
    for (int j = 0; j < 8; ++j) bv[j] = bias[j * 16 + l16];

    f32x4 acc[8];
#pragma unroll
    for (int j = 0; j < 8; ++j) acc[j] = 0.f;

    f32x4 aC[4], aN[4];   // adj fragments f32: [s*2], [s*2+1] = 8 k-values per s

#pragma unroll
    for (int s = 0; s < 2; ++s) {
        const float* p = adjw + s * 32 + quad * 8;
        aC[s * 2] = *(const f32x4*)p;
        aC[s * 2 + 1] = *(const f32x4*)(p + 4);
    }

#pragma unroll
    for (int kb = 0; kb < 16; ++kb) {
        // 1) B fragments for THIS step first: L2-hot; issuing before the HBM
        //    prefetch keeps their (in-order) vmcnt waits off the slow chain.
        bf16x8 bb[8][2];
#pragma unroll
        for (int j = 0; j < 8; ++j)
#pragma unroll
            for (int s = 0; s < 2; ++s)
                bb[j][s] = *(const bf16x8*)&stb[(size_t)(j * 16 + l16) * 1024 +
                                                kb * 64 + s * 32 + quad * 8];
        // 2) depth-1 adj prefetch for kb+1 (HBM ~900cy, hidden by this step)
        if (kb < 15) {
#pragma unroll
            for (int s = 0; s < 2; ++s) {
                const float* p = adjw + (kb + 1) * 64 + s * 32 + quad * 8;
                aN[s * 2] = *(const f32x4*)p;
                aN[s * 2 + 1] = *(const f32x4*)(p + 4);
            }
        }
        // 3) convert + MFMA (K-order per output: kb asc, s asc — unchanged)
        bf16x8 a0 = cvt8(aC[0], aC[1]);
        bf16x8 a1 = cvt8(aC[2], aC[3]);
#pragma unroll
        for (int j = 0; j < 8; ++j) {
            acc[j] = __builtin_amdgcn_mfma_f32_16x16x32_bf16(a0, bb[j][0], acc[j], 0, 0, 0);
            acc[j] = __builtin_amdgcn_mfma_f32_16x16x32_bf16(a1, bb[j][1], acc[j], 0, 0, 0);
        }
        // 4) rotate prefetch regs
#pragma unroll
        for (int i = 0; i < 4; ++i) aC[i] = aN[i];
    }

    float* outb = out + ((size_t)batch * 1024 + mbase) * 128;
#pragma unroll
    for (int j = 0; j < 8; ++j) {
        int n = j * 16 + l16;
#pragma unroll
        for (int r = 0; r < 4; ++r) {
            int m = wv * 16 + quad * 4 + r;
            float v = acc[j][r] + bv[j];
            outb[(size_t)m * 128 + n] = fmaxf(v, 0.f);
        }
    }
}

extern "C" void kernel_launch(void* const* d_in, const int* in_sizes, int n_in,
                              void* d_out, int out_size, void* d_ws, size_t ws_size,
                              hipStream_t stream) {
    const float* x = (const float*)d_in[0];
    const float* adj = (const float*)d_in[1];
    const float* W = (const float*)d_in[2];
    const float* b = (const float*)d_in[3];
    float* out = (float*)d_out;

    // ws layout: ST bf16 [32][128][1024] = 8 MiB, then WT bf16 [128][128] = 32 KiB
    unsigned short* ST = (unsigned short*)d_ws;
    unsigned short* WT = (unsigned short*)d_ws + (size_t)32 * 128 * 1024;

    k0_wt<<<64, 256, 0, stream>>>(W, WT);
    k1_support<<<512, 256, 0, stream>>>(x, WT, ST);
    k2_gcn<<<512, 256, 0, stream>>>(adj, ST, b, out);
}

// Round 6
// 229.216 us; speedup vs baseline: 1.1488x; 1.1488x over previous
//
#include <hip/hip_runtime.h>
#include <stdint.h>

// GCN: out = relu(adj @ (x @ W) + b)
// x:[32,1024,128] f32, adj:[32,1024,1024] f32, W:[128,128] f32, b:[128] f32
// v7: k2 staging via global_load_lds DMA (m97 structure).
//   Ledger: k2 v1/v2 (reg-round-trip LDS) 59-61us, v4 69, v5 67.6, stream 87,
//   v6 108 (VGPR=48: compiler sank every reg-dest load -> serial round trips).
//   Lesson: reg-dest load scheduling belongs to the compiler; DMA doesn't.
//   k2: adj staged as raw f32 (cvt after ds_read), ST staged bf16, dbuf,
//   8 fire-and-forget DMAs/thread/step, 2-barrier loop. DMA dest is lane-linear
//   (HW constraint) -> T2 swizzle done as: linear dest + pre-swizzled GLOBAL
//   source (chunk ^= row&7) + XOR'd ds_read addr (rule 21, G4-r268 pattern).
//   T1 XCD swizzle: 64 consecutive orig-blocks (4 batches) per XCD -> ST slice
//   L2-resident. MFMA K-order identical -> bit-identical output.
// k1 stays LDS-free streaming (~floor).

typedef short bf16x8 __attribute__((ext_vector_type(8)));       // 8 bf16 (4 VGPRs)
typedef float f32x4 __attribute__((ext_vector_type(4)));
typedef unsigned short u16x8 __attribute__((ext_vector_type(8)));

__device__ __forceinline__ unsigned short f2bf(float f) {
    uint32_t u = __builtin_bit_cast(uint32_t, f);
    u += 0x7FFFu + ((u >> 16) & 1u);   // RTNE
    return (unsigned short)(u >> 16);
}

__device__ __forceinline__ bf16x8 cvt8(f32x4 v0, f32x4 v1) {
    u16x8 p;
    p[0] = f2bf(v0.x); p[1] = f2bf(v0.y); p[2] = f2bf(v0.z); p[3] = f2bf(v0.w);
    p[4] = f2bf(v1.x); p[5] = f2bf(v1.y); p[6] = f2bf(v1.z); p[7] = f2bf(v1.w);
    return __builtin_bit_cast(bf16x8, p);
}

// async 16B global -> LDS DMA (no VGPR round trip; size must be literal 16)
#define GLD16(g, l)                                                         \
    __builtin_amdgcn_global_load_lds(                                       \
        (const __attribute__((address_space(1))) unsigned int*)(g),         \
        (__attribute__((address_space(3))) unsigned int*)(l), 16, 0, 0)

// ---------------- k0: WT[h][f] = bf16(W[f][h]) ----------------
__global__ __launch_bounds__(256) void k0_wt(const float* __restrict__ W,
                                             unsigned short* __restrict__ WT) {
    int o = blockIdx.x * 256 + threadIdx.x;  // flat over [h][f]
    int h = o >> 7, f = o & 127;
    WT[o] = f2bf(W[f * 128 + h]);
}

// ---------------- k1: ST[b][h][m] = sum_f WT[h][f] * x[b][m][f] ----------------
// D'[h][m] per block: 128 h x 64 m, K=128. LDS-free: A-frags direct from WT
// (bf16, L2-hot), B-frags direct from x rows (f32 -> cvt in reg).
__global__ __launch_bounds__(256) void k1_support(const float* __restrict__ x,
                                                  const unsigned short* __restrict__ WT,
                                                  unsigned short* __restrict__ ST) {
    int t = threadIdx.x;
    int wv = t >> 6, lane = t & 63, l16 = lane & 15, quad = lane >> 4;
    int wave_h = (wv & 1) * 64, wave_m = (wv >> 1) * 32;
    int node_base = blockIdx.x * 64;
    const float* xb = x + (size_t)node_base * 128;

    f32x4 acc[4][2];
#pragma unroll
    for (int ht = 0; ht < 4; ++ht)
#pragma unroll
        for (int mt = 0; mt < 2; ++mt) acc[ht][mt] = 0.f;

#pragma unroll
    for (int s = 0; s < 4; ++s) {
        int ko = s * 32 + quad * 8;
        bf16x8 a[4], bb[2];
#pragma unroll
        for (int ht = 0; ht < 4; ++ht)
            a[ht] = *(const bf16x8*)&WT[(wave_h + ht * 16 + l16) * 128 + ko];
#pragma unroll
        for (int mt = 0; mt < 2; ++mt) {
            const float* xr = xb + (size_t)(wave_m + mt * 16 + l16) * 128 + ko;
            bb[mt] = cvt8(*(const f32x4*)xr, *(const f32x4*)(xr + 4));
        }
#pragma unroll
        for (int ht = 0; ht < 4; ++ht)
#pragma unroll
            for (int mt = 0; mt < 2; ++mt)
                acc[ht][mt] = __builtin_amdgcn_mfma_f32_16x16x32_bf16(
                    a[ht], bb[mt], acc[ht][mt], 0, 0, 0);
    }

    int batch = blockIdx.x >> 4;
    int m_in_b = (blockIdx.x & 15) * 64;
#pragma unroll
    for (int ht = 0; ht < 4; ++ht)
#pragma unroll
        for (int mt = 0; mt < 2; ++mt) {
            int mcol = wave_m + mt * 16 + l16;
#pragma unroll
            for (int r = 0; r < 4; ++r) {
                int h = wave_h + ht * 16 + quad * 4 + r;
                ST[(((size_t)batch * 128 + h) << 10) + m_in_b + mcol] =
                    f2bf(acc[ht][mt][r]);
            }
        }
}

// ---------------- k2: out[b][m][n] = relu(sum_k adj[b][m][k]*S[b][k][n] + bias[n]) ----
// 64m x 128n per block, grid 512 (XCD-swizzled), 4 waves (32m x 64n), BK=64.
// LDS (dbuf, linear, swizzled content):
//   As[2]: [m=64][16 chunks of 16B] f32  (row 256B), content chunk c at slot c^(m&7)
//   Bs[2]: [n=128][8 chunks of 16B] bf16 (row 128B), content chunk c at slot c^(n&7)
__global__ __launch_bounds__(256, 2) void k2_gcn(const float* __restrict__ adj,
                                                 const unsigned short* __restrict__ ST,
                                                 const float* __restrict__ bias,
                                                 float* __restrict__ out) {
    __shared__ __align__(16) unsigned char As[2][64 * 256];    // f32 tiles, 16KB ea
    __shared__ __align__(16) unsigned char Bs[2][128 * 128];   // bf16 tiles, 16KB ea
    int t = threadIdx.x;
    int bid = (int)blockIdx.x;
    int orig = (bid & 7) * 64 + (bid >> 3);   // T1: 4 batches per XCD, bijective
    int batch = orig >> 4;
    int mbase = (orig & 15) * 64;
    int wv = t >> 6, lane = t & 63, l16 = lane & 15, quad = lane >> 4;
    int wave_m = (wv & 1) * 32, wave_n = (wv >> 1) * 64;

    const char* adjB = (const char*)(adj + ((size_t)batch * 1024 + mbase) * 1024);
    const char* stB  = (const char*)(ST + ((size_t)batch * 128) * 1024);

    // staging: DMA dest linear (o = i*4096 + t*16); global source pre-swizzled.
    // As: row m = i*16 + (t>>4), content chunk = (t&15) ^ (m&7); m&7 = (t>>4)&7
    int cA = (t & 15) ^ ((t >> 4) & 7);
    const char* srcA0 = adjB + (size_t)(t >> 4) * 4096 + cA * 16;  // +i*65536 +kb*256
    // Bs: row n = i*32 + (t>>3), content chunk = (t&7) ^ (n&7); n&7 = (t>>3)&7
    int cB = (t & 7) ^ ((t >> 3) & 7);
    const char* srcB0 = stB + (size_t)(t >> 3) * 2048 + cB * 16;   // +i*65536 +kb*128

    float bv[4];
#pragma unroll
    for (int j = 0; j < 4; ++j) bv[j] = bias[wave_n + j * 16 + l16];

    f32x4 acc[2][4];
#pragma unroll
    for (int i = 0; i < 2; ++i)
#pragma unroll
        for (int j = 0; j < 4; ++j) acc[i][j] = 0.f;

    // read-side bases: row byte offsets; chunk index XOR'd with l16&7
    int aswz = l16 & 7;
    int arow = (wave_m + l16) * 256;   // + im*4096 for im-th 16-row group
    int brow = (wave_n + l16) * 128;   // + j*2048 for j-th 16-row group

    auto STAGE = [&](int buf, int kb) {
        char* dA = (char*)As[buf] + t * 16;
        const char* sA = srcA0 + kb * 256;
#pragma unroll
        for (int i = 0; i < 4; ++i) GLD16(sA + i * 65536, dA + i * 4096);
        char* dB = (char*)Bs[buf] + t * 16;
        const char* sB = srcB0 + kb * 128;
#pragma unroll
        for (int i = 0; i < 4; ++i) GLD16(sB + i * 65536, dB + i * 4096);
    };

    auto COMPUTE = [&](int buf) {
#pragma unroll
        for (int s = 0; s < 2; ++s) {
            bf16x8 afr[2];
#pragma unroll
            for (int im = 0; im < 2; ++im) {
                int c0 = (s * 8 + quad * 2) ^ aswz;        // k ko..ko+3 (f32)
                int c1 = c0 ^ 1;                           // k ko+4..ko+7
                f32x4 lo = *(const f32x4*)(As[buf] + arow + im * 4096 + c0 * 16);
                f32x4 hi = *(const f32x4*)(As[buf] + arow + im * 4096 + c1 * 16);
                afr[im] = cvt8(lo, hi);
            }
            bf16x8 bfr[4];
#pragma unroll
            for (int j = 0; j < 4; ++j) {
                int c = (s * 4 + quad) ^ aswz;
                bfr[j] = *(const bf16x8*)(Bs[buf] + brow + j * 2048 + c * 16);
            }
#pragma unroll
            for (int im = 0; im < 2; ++im)
#pragma unroll
                for (int j = 0; j < 4; ++j)
                    acc[im][j] = __builtin_amdgcn_mfma_f32_16x16x32_bf16(
                        afr[im], bfr[j], acc[im][j], 0, 0, 0);
        }
    };

    STAGE(0, 0);
    __syncthreads();              // drains DMA vmcnt -> tile 0 ready
    for (int kb = 0; kb < 16; ++kb) {
        int cur = kb & 1;
        if (kb < 15) STAGE(cur ^ 1, kb + 1);   // fire-and-forget; lands during compute
        COMPUTE(cur);
        if (kb < 15) __syncthreads();          // m97 2-barrier step
    }

    float* outb = out + ((size_t)batch * 1024 + mbase) * 128;
#pragma unroll
    for (int i = 0; i < 2; ++i)
#pragma unroll
        for (int j = 0; j < 4; ++j) {
            int n = wave_n + j * 16 + l16;
#pragma unroll
            for (int r = 0; r < 4; ++r) {
                int m = wave_m + i * 16 + quad * 4 + r;
                float v = acc[i][j][r] + bv[j];
                outb[(size_t)m * 128 + n] = fmaxf(v, 0.f);
            }
        }
}

extern "C" void kernel_launch(void* const* d_in, const int* in_sizes, int n_in,
                              void* d_out, int out_size, void* d_ws, size_t ws_size,
                              hipStream_t stream) {
    const float* x = (const float*)d_in[0];
    const float* adj = (const float*)d_in[1];
    const float* W = (const float*)d_in[2];
    const float* b = (const float*)d_in[3];
    float* out = (float*)d_out;

    // ws layout: ST bf16 [32][128][1024] = 8 MiB, then WT bf16 [128][128] = 32 KiB
    unsigned short* ST = (unsigned short*)d_ws;
    unsigned short* WT = (unsigned short*)d_ws + (size_t)32 * 128 * 1024;

    k0_wt<<<64, 256, 0, stream>>>(W, WT);
    k1_support<<<512, 256, 0, stream>>>(x, WT, ST);
    k2_gcn<<<512, 256, 0, stream>>>(adj, ST, b, out);
}